// Round 4
// baseline (478.613 us; speedup 1.0000x reference)
//
#include <hip/hip_runtime.h>

#define H 128
#define RREL 8
#define KTOT 1152  // RREL*H + H
#define TM 64

typedef short bf16x8 __attribute__((ext_vector_type(8)));
typedef float f32x4 __attribute__((ext_vector_type(4)));
typedef unsigned short u16x8 __attribute__((ext_vector_type(8)));

static __device__ __forceinline__ unsigned short f2bf(float f) {
    unsigned int u = __float_as_uint(f);
    unsigned int r = (u + 0x7fffu + ((u >> 16) & 1u)) >> 16;
    return (unsigned short)r;
}
static __device__ __forceinline__ float bf2f(unsigned short u) {
    return __uint_as_float(((unsigned int)u) << 16);
}

__global__ void zero_kernel(int* p, long n) {
    long i = (long)blockIdx.x * blockDim.x + threadIdx.x;
    long stride = (long)gridDim.x * blockDim.x;
    for (; i < n; i += stride) p[i] = 0;
}

__global__ void count_kernel(const int* __restrict__ ei, const int* __restrict__ et,
                             int* __restrict__ cnt, int E) {
    int e = blockIdx.x * 256 + threadIdx.x;
    if (e >= E) return;
    int d = ei[E + e];
    int r = et[e];
    atomicAdd(&cnt[(size_t)d * RREL + r], 1);
}

__global__ void scan_block_kernel(const int* __restrict__ cnt, int* __restrict__ rploc,
                                  int* __restrict__ bsum, int N) {
    __shared__ int s[256];
    int t = threadIdx.x;
    int d = blockIdx.x * 256 + t;
    int v = 0;
    if (d < N) {
#pragma unroll
        for (int r = 0; r < RREL; ++r) v += cnt[(size_t)d * RREL + r];
    }
    s[t] = v;
    __syncthreads();
#pragma unroll
    for (int off = 1; off < 256; off <<= 1) {
        int u = 0;
        if (t >= off) u = s[t - off];
        __syncthreads();
        s[t] += u;
        __syncthreads();
    }
    if (d < N) rploc[d] = s[t] - v;
    if (t == 255) bsum[blockIdx.x] = s[255];
}

__global__ void scan_top_kernel(const int* __restrict__ bsum, int* __restrict__ boff, int nb) {
    __shared__ int s[256];
    int t = threadIdx.x;
    int v = (t < nb) ? bsum[t] : 0;
    s[t] = v;
    __syncthreads();
#pragma unroll
    for (int off = 1; off < 256; off <<= 1) {
        int u = 0;
        if (t >= off) u = s[t - off];
        __syncthreads();
        s[t] += u;
        __syncthreads();
    }
    boff[t] = s[t] - v;
}

__global__ void finalize_kernel(const int* __restrict__ cnt, const int* __restrict__ rploc,
                                const int* __restrict__ boff, int* __restrict__ rowptr2,
                                float* __restrict__ inv, int N) {
    int d = blockIdx.x * 256 + threadIdx.x;
    if (d >= N) return;
    int run = rploc[d] + boff[d >> 8];
#pragma unroll
    for (int r = 0; r < RREL; ++r) {
        int c = cnt[(size_t)d * RREL + r];
        rowptr2[(size_t)d * RREL + r] = run;
        inv[(size_t)d * RREL + r] = 1.0f / (float)max(c, 1);
        run += c;
    }
    if (d == N - 1) rowptr2[(size_t)N * RREL] = run;
}

__global__ void fill_kernel(const int* __restrict__ ei, const int* __restrict__ et,
                            int* __restrict__ cursor, const int* __restrict__ rowptr2,
                            int* __restrict__ ssrc, int E) {
    int e = blockIdx.x * 256 + threadIdx.x;
    if (e >= E) return;
    int d = ei[E + e];
    int r = et[e];
    int bin = d * RREL + r;
    int pos = rowptr2[bin] + atomicAdd(&cursor[bin], 1);
    ssrc[pos] = ei[e];
}

__global__ void tobf_kernel(const float* __restrict__ x, unsigned short* __restrict__ xb, long n) {
    long i = (long)blockIdx.x * blockDim.x + threadIdx.x;
    long stride = (long)gridDim.x * blockDim.x;
    for (; i < n; i += stride) xb[i] = f2bf(x[i]);
}

// WT[f][k], k = r*128+d for k<1024 (W[r][d][f]), else root[k-1024][f]
__global__ void wcat_kernel(const float* __restrict__ W1, const float* __restrict__ r1,
                            const float* __restrict__ W2, const float* __restrict__ r2,
                            unsigned short* __restrict__ WT1, unsigned short* __restrict__ WT2) {
    int id = blockIdx.x * 256 + threadIdx.x;
    if (id >= 2 * H * KTOT) return;
    int b = id / (H * KTOT);
    int rem = id - b * (H * KTOT);
    int f = rem / KTOT;
    int k = rem - f * KTOT;
    const float* W = b ? W2 : W1;
    const float* rt = b ? r2 : r1;
    float v = (k < RREL * H) ? W[(size_t)(k >> 7) * H * H + (size_t)(k & 127) * H + f]
                             : rt[(size_t)(k - RREL * H) * H + f];
    (b ? WT2 : WT1)[(size_t)f * KTOT + k] = f2bf(v);
}

// Fused gather + GEMM: block handles 64 dst rows x 128 out cols, K = 9 chunks of 128.
// Chunk r<8: As[row][f] = inv[d][r] * sum_{edges of bin (d,r)} xb[src][f]; chunk 8: As = xb[d].
__global__ __launch_bounds__(256) void fused_kernel(const unsigned short* __restrict__ xb,
                                                    const unsigned short* __restrict__ WT,
                                                    const float* __restrict__ bias,
                                                    const float* __restrict__ inv,
                                                    const int* __restrict__ rowptr2,
                                                    const int* __restrict__ ssrc,
                                                    float* __restrict__ outf,
                                                    unsigned short* __restrict__ outb,
                                                    int N, int relu) {
    __shared__ unsigned short As[TM][136];
    __shared__ unsigned short Bs[128][136];
    const int t = threadIdx.x;
    const int w = t >> 6, l = t & 63;
    const int m_base = blockIdx.x * TM;
    const int g = l >> 4;      // 16-lane group within wave
    const int fl = l & 15;     // lane within group
    const int kc = fl * 8;     // 8-bf16 feature offset
    const f32x4 fz = {0.f, 0.f, 0.f, 0.f};
    const u16x8 uz = {0, 0, 0, 0, 0, 0, 0, 0};
    f32x4 acc[8];
#pragma unroll
    for (int n = 0; n < 8; ++n) acc[n] = fz;

    for (int r = 0; r < 9; ++r) {
        // stage Bs[f][k] = WT[f][r*128+k]  (128x128)
#pragma unroll
        for (int p = 0; p < 8; ++p) {
            int c = p * 256 + t;
            int f = c >> 4, k8 = (c & 15) * 8;
            *(u16x8*)&Bs[f][k8] = *(const u16x8*)&WT[(size_t)f * KTOT + r * H + k8];
        }
        if (r < RREL) {
            // wave w gathers rows [w*16, w*16+16); lane l<16 preloads bin bounds for row l
            int begv = 0, endv = 0;
            float invv = 1.0f;
            int dpre = m_base + w * 16 + l;
            if (l < 16 && dpre < N) {
                begv = rowptr2[(size_t)dpre * RREL + r];
                endv = rowptr2[(size_t)dpre * RREL + r + 1];
                invv = inv[(size_t)dpre * RREL + r];
            }
#pragma unroll
            for (int step = 0; step < 4; ++step) {
                int idx = step * 4 + g;   // row-in-group 0..15, one row per 16-lane group
                int beg = __shfl(begv, idx);
                int end = __shfl(endv, idx);
                float iv = __shfl(invv, idx);
                float af[8] = {};
                for (int i = beg; i < end; ++i) {
                    int s = ssrc[i];
                    u16x8 v = *(const u16x8*)&xb[(size_t)s * H + kc];
#pragma unroll
                    for (int j = 0; j < 8; ++j) af[j] += bf2f((unsigned short)v[j]);
                }
                u16x8 o;
#pragma unroll
                for (int j = 0; j < 8; ++j) o[j] = f2bf(af[j] * iv);
                *(u16x8*)&As[w * 16 + idx][kc] = o;
            }
        } else {
            // root chunk: As[row] = xb[m_base+row]
#pragma unroll
            for (int p = 0; p < 4; ++p) {
                int c = p * 256 + t;
                int row = c >> 4, k8 = (c & 15) * 8;
                int gn = m_base + row;
                u16x8 v = uz;
                if (gn < N) v = *(const u16x8*)&xb[(size_t)gn * H + k8];
                *(u16x8*)&As[row][k8] = v;
            }
        }
        __syncthreads();
        const int quad = l >> 4, mrow = l & 15;
#pragma unroll
        for (int ks = 0; ks < 4; ++ks) {
            int kl = ks * 32 + quad * 8;
            bf16x8 a = *(const bf16x8*)&As[w * 16 + mrow][kl];
#pragma unroll
            for (int n = 0; n < 8; ++n) {
                bf16x8 b = *(const bf16x8*)&Bs[n * 16 + mrow][kl];
                acc[n] = __builtin_amdgcn_mfma_f32_16x16x32_bf16(a, b, acc[n], 0, 0, 0);
            }
        }
        __syncthreads();
    }
    const int colb = l & 15, quad = l >> 4;
#pragma unroll
    for (int n = 0; n < 8; ++n) {
        int col = n * 16 + colb;
        float bv = bias[col];
#pragma unroll
        for (int i = 0; i < 4; ++i) {
            int gn = m_base + w * 16 + quad * 4 + i;
            if (gn < N) {
                float v = acc[n][i] + bv;
                if (relu) v = fmaxf(v, 0.f);
                if (outf) outf[(size_t)gn * H + col] = v;
                else outb[(size_t)gn * H + col] = f2bf(v);
            }
        }
    }
}

extern "C" void kernel_launch(void* const* d_in, const int* in_sizes, int n_in,
                              void* d_out, int out_size, void* d_ws, size_t ws_size,
                              hipStream_t stream) {
    const int* edge_index = (const int*)d_in[0];
    const int* edge_type  = (const int*)d_in[1];
    const float* node_emb = (const float*)d_in[2];
    const float* W1    = (const float*)d_in[3];
    const float* root1 = (const float*)d_in[4];
    const float* b1    = (const float*)d_in[5];
    const float* W2    = (const float*)d_in[6];
    const float* root2 = (const float*)d_in[7];
    const float* b2    = (const float*)d_in[8];
    float* out = (float*)d_out;

    const int E = in_sizes[1];
    const int N = in_sizes[2] / H;

    char* base = (char*)d_ws;
    size_t off = 0;
    auto take = [&](size_t bytes) { size_t o = off; off = (off + bytes + 63) & ~(size_t)63; return o; };
    int*   cnt     = (int*)  (base + take((size_t)N * RREL * 4));
    int*   cursor  = (int*)  (base + take((size_t)N * RREL * 4));
    int*   rploc   = (int*)  (base + take((size_t)N * 4));
    int*   bsum    = (int*)  (base + take(256 * 4));
    int*   boff    = (int*)  (base + take(256 * 4));
    int*   rowptr2 = (int*)  (base + take(((size_t)N * RREL + 1) * 4));
    float* inv     = (float*)(base + take((size_t)N * RREL * 4));
    int*   ssrc    = (int*)  (base + take((size_t)E * 4));
    unsigned short* WT1 = (unsigned short*)(base + take((size_t)H * KTOT * 2));
    unsigned short* WT2 = (unsigned short*)(base + take((size_t)H * KTOT * 2));
    unsigned short* xb  = (unsigned short*)(base + take((size_t)N * H * 2));
    unsigned short* hb  = (unsigned short*)(base + take((size_t)N * H * 2));

    const int nbScan = (N + 255) / 256;
    const int gm = (N + TM - 1) / TM;

    zero_kernel<<<512, 256, 0, stream>>>(cnt, (long)N * RREL * 2);  // cnt + cursor
    count_kernel<<<(E + 255) / 256, 256, 0, stream>>>(edge_index, edge_type, cnt, E);
    scan_block_kernel<<<nbScan, 256, 0, stream>>>(cnt, rploc, bsum, N);
    scan_top_kernel<<<1, 256, 0, stream>>>(bsum, boff, nbScan);
    finalize_kernel<<<nbScan, 256, 0, stream>>>(cnt, rploc, boff, rowptr2, inv, N);
    fill_kernel<<<(E + 255) / 256, 256, 0, stream>>>(edge_index, edge_type, cursor, rowptr2, ssrc, E);
    wcat_kernel<<<(2 * H * KTOT + 255) / 256, 256, 0, stream>>>(W1, root1, W2, root2, WT1, WT2);
    tobf_kernel<<<1024, 256, 0, stream>>>(node_emb, xb, (long)N * H);

    fused_kernel<<<gm, 256, 0, stream>>>(xb, WT1, b1, inv, rowptr2, ssrc, nullptr, hb, N, 1);
    fused_kernel<<<gm, 256, 0, stream>>>(hb, WT2, b2, inv, rowptr2, ssrc, out, nullptr, N, 0);
}

// Round 5
// 346.979 us; speedup vs baseline: 1.3794x; 1.3794x over previous
//
#include <hip/hip_runtime.h>

#define H 128
#define RREL 8
#define KREL 1024   // RREL*H — A-matrix K extent (root read directly from xb)
#define KTOT 1152   // RREL*H + H — WT K extent

typedef short bf16x8 __attribute__((ext_vector_type(8)));
typedef float f32x4 __attribute__((ext_vector_type(4)));
typedef unsigned short u16x8 __attribute__((ext_vector_type(8)));

static __device__ __forceinline__ unsigned short f2bf(float f) {
    unsigned int u = __float_as_uint(f);
    unsigned int r = (u + 0x7fffu + ((u >> 16) & 1u)) >> 16;
    return (unsigned short)r;
}
static __device__ __forceinline__ float bf2f(unsigned short u) {
    return __uint_as_float(((unsigned int)u) << 16);
}

__global__ void zero_kernel(int* p, long n) {
    long i = (long)blockIdx.x * blockDim.x + threadIdx.x;
    long stride = (long)gridDim.x * blockDim.x;
    for (; i < n; i += stride) p[i] = 0;
}

__global__ void count_kernel(const int* __restrict__ ei, const int* __restrict__ et,
                             int* __restrict__ cnt, int E) {
    int e = blockIdx.x * 256 + threadIdx.x;
    if (e >= E) return;
    int d = ei[E + e];
    int r = et[e];
    atomicAdd(&cnt[(size_t)d * RREL + r], 1);
}

__global__ void scan_block_kernel(const int* __restrict__ cnt, int* __restrict__ rploc,
                                  int* __restrict__ bsum, int N) {
    __shared__ int s[256];
    int t = threadIdx.x;
    int d = blockIdx.x * 256 + t;
    int v = 0;
    if (d < N) {
#pragma unroll
        for (int r = 0; r < RREL; ++r) v += cnt[(size_t)d * RREL + r];
    }
    s[t] = v;
    __syncthreads();
#pragma unroll
    for (int off = 1; off < 256; off <<= 1) {
        int u = 0;
        if (t >= off) u = s[t - off];
        __syncthreads();
        s[t] += u;
        __syncthreads();
    }
    if (d < N) rploc[d] = s[t] - v;
    if (t == 255) bsum[blockIdx.x] = s[255];
}

__global__ void scan_top_kernel(const int* __restrict__ bsum, int* __restrict__ boff, int nb) {
    __shared__ int s[256];
    int t = threadIdx.x;
    int v = (t < nb) ? bsum[t] : 0;
    s[t] = v;
    __syncthreads();
#pragma unroll
    for (int off = 1; off < 256; off <<= 1) {
        int u = 0;
        if (t >= off) u = s[t - off];
        __syncthreads();
        s[t] += u;
        __syncthreads();
    }
    boff[t] = s[t] - v;
}

__global__ void finalize_kernel(const int* __restrict__ cnt, const int* __restrict__ rploc,
                                const int* __restrict__ boff, int* __restrict__ rowptr2,
                                float* __restrict__ inv, int N) {
    int d = blockIdx.x * 256 + threadIdx.x;
    if (d >= N) return;
    int run = rploc[d] + boff[d >> 8];
#pragma unroll
    for (int r = 0; r < RREL; ++r) {
        int c = cnt[(size_t)d * RREL + r];
        rowptr2[(size_t)d * RREL + r] = run;
        inv[(size_t)d * RREL + r] = 1.0f / (float)max(c, 1);
        run += c;
    }
    if (d == N - 1) rowptr2[(size_t)N * RREL] = run;
}

__global__ void fill_kernel(const int* __restrict__ ei, const int* __restrict__ et,
                            int* __restrict__ cursor, const int* __restrict__ rowptr2,
                            int* __restrict__ ssrc, int E) {
    int e = blockIdx.x * 256 + threadIdx.x;
    if (e >= E) return;
    int d = ei[E + e];
    int r = et[e];
    int bin = d * RREL + r;
    int pos = rowptr2[bin] + atomicAdd(&cursor[bin], 1);
    ssrc[pos] = ei[e];
}

__global__ void tobf_kernel(const float* __restrict__ x, unsigned short* __restrict__ xb, long n) {
    long i = (long)blockIdx.x * blockDim.x + threadIdx.x;
    long stride = (long)gridDim.x * blockDim.x;
    for (; i < n; i += stride) xb[i] = f2bf(x[i]);
}

// WT[f][k], k = r*128+d for k<1024 (W[r][d][f]), else root[k-1024][f]
__global__ void wcat_kernel(const float* __restrict__ W1, const float* __restrict__ r1,
                            const float* __restrict__ W2, const float* __restrict__ r2,
                            unsigned short* __restrict__ WT1, unsigned short* __restrict__ WT2) {
    int id = blockIdx.x * 256 + threadIdx.x;
    if (id >= 2 * H * KTOT) return;
    int b = id / (H * KTOT);
    int rem = id - b * (H * KTOT);
    int f = rem / KTOT;
    int k = rem - f * KTOT;
    const float* W = b ? W2 : W1;
    const float* rt = b ? r2 : r1;
    float v = (k < RREL * H) ? W[(size_t)(k >> 7) * H * H + (size_t)(k & 127) * H + f]
                             : rt[(size_t)(k - RREL * H) * H + f];
    (b ? WT2 : WT1)[(size_t)f * KTOT + k] = f2bf(v);
}

// one 16-lane group per (dst, relation) bin; 16 groups per block; u16x8 row loads
__global__ __launch_bounds__(256) void gather_kernel(const unsigned short* __restrict__ xb,
                                                     const float* __restrict__ inv,
                                                     const int* __restrict__ rowptr2,
                                                     const int* __restrict__ ssrc,
                                                     unsigned short* __restrict__ A,
                                                     int n0, int n1) {
    const int t = threadIdx.x;
    int gid = blockIdx.x * 16 + (t >> 4);
    int bin = n0 * RREL + gid;
    if (bin >= n1 * RREL) return;
    const int kc = (t & 15) * 8;
    int beg = rowptr2[bin];
    int end = rowptr2[bin + 1];
    float iv = inv[bin];
    float af[8] = {};
    int i = beg;
    for (; i + 1 < end; i += 2) {
        int s0 = ssrc[i];
        int s1 = ssrc[i + 1];
        u16x8 v0 = *(const u16x8*)&xb[(size_t)s0 * H + kc];
        u16x8 v1 = *(const u16x8*)&xb[(size_t)s1 * H + kc];
#pragma unroll
        for (int j = 0; j < 8; ++j) af[j] += bf2f((unsigned short)v0[j]) + bf2f((unsigned short)v1[j]);
    }
    if (i < end) {
        int s0 = ssrc[i];
        u16x8 v0 = *(const u16x8*)&xb[(size_t)s0 * H + kc];
#pragma unroll
        for (int j = 0; j < 8; ++j) af[j] += bf2f((unsigned short)v0[j]);
    }
    u16x8 o;
#pragma unroll
    for (int j = 0; j < 8; ++j) o[j] = f2bf(af[j] * iv);
    // bin = d*8+r → A row (d-n0), K-offset r*128
    int drel = bin - n0 * RREL;
    *(u16x8*)&A[(size_t)(drel >> 3) * KREL + (drel & 7) * H + kc] = o;
}

// out[n][f] = act(sum_k Arow[k]*B[k][f] + bias[f]); K<1024 from A, K>=1024 from xb (root)
__global__ __launch_bounds__(256) void gemm_kernel(const unsigned short* __restrict__ A,
                                                   const unsigned short* __restrict__ xb,
                                                   const unsigned short* __restrict__ WT,
                                                   const float* __restrict__ bias,
                                                   float* __restrict__ outf,
                                                   unsigned short* __restrict__ outb,
                                                   int n0, int n1, int relu) {
    __shared__ unsigned short As[128][72];
    __shared__ unsigned short Bs[128][72];
    const int t = threadIdx.x;
    const int w = t >> 6, l = t & 63;
    const int m_base = blockIdx.x * 128;
    const f32x4 fz = {0.f, 0.f, 0.f, 0.f};
    f32x4 acc[2][8];
#pragma unroll
    for (int mi = 0; mi < 2; ++mi)
#pragma unroll
        for (int n = 0; n < 8; ++n) acc[mi][n] = fz;

    const int rr = t >> 3;
    const int kc = (t & 7) * 8;
    const u16x8 uz = {0, 0, 0, 0, 0, 0, 0, 0};

    for (int kk = 0; kk < KTOT; kk += 64) {
#pragma unroll
        for (int p = 0; p < 4; ++p) {
            int row = p * 32 + rr;
            int gn = n0 + m_base + row;
            u16x8 va = uz;
            if (gn < n1) {
                if (kk < KREL)
                    va = *(const u16x8*)&A[(size_t)(gn - n0) * KREL + kk + kc];
                else
                    va = *(const u16x8*)&xb[(size_t)gn * H + (kk - KREL) + kc];
            }
            *(u16x8*)&As[row][kc] = va;
            u16x8 vb = *(const u16x8*)&WT[(size_t)row * KTOT + kk + kc];
            *(u16x8*)&Bs[row][kc] = vb;
        }
        __syncthreads();
#pragma unroll
        for (int ks = 0; ks < 2; ++ks) {
            int kl = ks * 32 + (l >> 4) * 8;
            bf16x8 a0 = *(const bf16x8*)&As[w * 32 + (l & 15)][kl];
            bf16x8 a1 = *(const bf16x8*)&As[w * 32 + 16 + (l & 15)][kl];
#pragma unroll
            for (int n = 0; n < 8; ++n) {
                bf16x8 b = *(const bf16x8*)&Bs[n * 16 + (l & 15)][kl];
                acc[0][n] = __builtin_amdgcn_mfma_f32_16x16x32_bf16(a0, b, acc[0][n], 0, 0, 0);
                acc[1][n] = __builtin_amdgcn_mfma_f32_16x16x32_bf16(a1, b, acc[1][n], 0, 0, 0);
            }
        }
        __syncthreads();
    }
    const int colb = l & 15, quad = l >> 4;
#pragma unroll
    for (int mi = 0; mi < 2; ++mi) {
#pragma unroll
        for (int n = 0; n < 8; ++n) {
            int col = n * 16 + colb;
            float bv = bias[col];
#pragma unroll
            for (int i = 0; i < 4; ++i) {
                int gn = n0 + m_base + w * 32 + mi * 16 + quad * 4 + i;
                if (gn < n1) {
                    float v = acc[mi][n][i] + bv;
                    if (relu) v = fmaxf(v, 0.f);
                    if (outf) outf[(size_t)gn * H + col] = v;
                    else outb[(size_t)gn * H + col] = f2bf(v);
                }
            }
        }
    }
}

extern "C" void kernel_launch(void* const* d_in, const int* in_sizes, int n_in,
                              void* d_out, int out_size, void* d_ws, size_t ws_size,
                              hipStream_t stream) {
    const int* edge_index = (const int*)d_in[0];
    const int* edge_type  = (const int*)d_in[1];
    const float* node_emb = (const float*)d_in[2];
    const float* W1    = (const float*)d_in[3];
    const float* root1 = (const float*)d_in[4];
    const float* b1    = (const float*)d_in[5];
    const float* W2    = (const float*)d_in[6];
    const float* root2 = (const float*)d_in[7];
    const float* b2    = (const float*)d_in[8];
    float* out = (float*)d_out;

    const int E = in_sizes[1];
    const int N = in_sizes[2] / H;

    char* base = (char*)d_ws;
    size_t off = 0;
    auto take = [&](size_t bytes) { size_t o = off; off = (off + bytes + 63) & ~(size_t)63; return o; };
    int*   cnt     = (int*)  (base + take((size_t)N * RREL * 4));
    int*   cursor  = (int*)  (base + take((size_t)N * RREL * 4));
    int*   rploc   = (int*)  (base + take((size_t)N * 4));
    int*   bsum    = (int*)  (base + take(256 * 4));
    int*   boff    = (int*)  (base + take(256 * 4));
    int*   rowptr2 = (int*)  (base + take(((size_t)N * RREL + 1) * 4));
    float* inv     = (float*)(base + take((size_t)N * RREL * 4));
    int*   ssrc    = (int*)  (base + take((size_t)E * 4));
    unsigned short* WT1 = (unsigned short*)(base + take((size_t)H * KTOT * 2));
    unsigned short* WT2 = (unsigned short*)(base + take((size_t)H * KTOT * 2));
    unsigned short* xb  = (unsigned short*)(base + take((size_t)N * H * 2));
    unsigned short* hb  = (unsigned short*)(base + take((size_t)N * H * 2));
    size_t a_off = off;
    unsigned short* A = (unsigned short*)(base + a_off);

    size_t avail = (ws_size > a_off) ? (ws_size - a_off) : 0;
    int chunk = N;
    while ((size_t)((chunk + 127) & ~127) * KREL * 2 > avail && chunk > 1024) chunk = (chunk + 1) / 2;
    chunk = (chunk + 127) & ~127;

    const int nbScan = (N + 255) / 256;

    zero_kernel<<<512, 256, 0, stream>>>(cnt, (long)N * RREL * 2);  // cnt + cursor
    count_kernel<<<(E + 255) / 256, 256, 0, stream>>>(edge_index, edge_type, cnt, E);
    scan_block_kernel<<<nbScan, 256, 0, stream>>>(cnt, rploc, bsum, N);
    scan_top_kernel<<<1, 256, 0, stream>>>(bsum, boff, nbScan);
    finalize_kernel<<<nbScan, 256, 0, stream>>>(cnt, rploc, boff, rowptr2, inv, N);
    fill_kernel<<<(E + 255) / 256, 256, 0, stream>>>(edge_index, edge_type, cursor, rowptr2, ssrc, E);
    wcat_kernel<<<(2 * H * KTOT + 255) / 256, 256, 0, stream>>>(W1, root1, W2, root2, WT1, WT2);
    tobf_kernel<<<1024, 256, 0, stream>>>(node_emb, xb, (long)N * H);

    // layer 1: xb -> hb = relu(A1 @ [W1;root1] + b1)  (bf16 out)
    for (int n0 = 0; n0 < N; n0 += chunk) {
        int n1 = (n0 + chunk < N) ? n0 + chunk : N;
        int rows = n1 - n0;
        gather_kernel<<<(rows * RREL + 15) / 16, 256, 0, stream>>>(xb, inv, rowptr2, ssrc, A, n0, n1);
        gemm_kernel<<<(rows + 127) / 128, 256, 0, stream>>>(A, xb, WT1, b1, nullptr, hb, n0, n1, 1);
    }
    // layer 2: hb -> out = A2 @ [W2;root2] + b2  (fp32 out)
    for (int n0 = 0; n0 < N; n0 += chunk) {
        int n1 = (n0 + chunk < N) ? n0 + chunk : N;
        int rows = n1 - n0;
        gather_kernel<<<(rows * RREL + 15) / 16, 256, 0, stream>>>(hb, inv, rowptr2, ssrc, A, n0, n1);
        gemm_kernel<<<(rows + 127) / 128, 256, 0, stream>>>(A, hb, WT2, b2, out, nullptr, n0, n1, 0);
    }
}

// Round 6
// 331.985 us; speedup vs baseline: 1.4417x; 1.0452x over previous
//
#include <hip/hip_runtime.h>

#define H 128
#define RREL 8
#define NJ 9        // 8 relations + root

typedef short bf16x8 __attribute__((ext_vector_type(8)));
typedef float f32x4 __attribute__((ext_vector_type(4)));
typedef unsigned short u16x8 __attribute__((ext_vector_type(8)));

static __device__ __forceinline__ unsigned short f2bf(float f) {
    unsigned int u = __float_as_uint(f);
    unsigned int r = (u + 0x7fffu + ((u >> 16) & 1u)) >> 16;
    return (unsigned short)r;
}
static __device__ __forceinline__ float bf2f(unsigned short u) {
    return __uint_as_float(((unsigned int)u) << 16);
}

__global__ void zero_kernel(int* p, long n) {
    long i = (long)blockIdx.x * blockDim.x + threadIdx.x;
    long stride = (long)gridDim.x * blockDim.x;
    for (; i < n; i += stride) p[i] = 0;
}

__global__ void count_kernel(const int* __restrict__ ei, const int* __restrict__ et,
                             int* __restrict__ cnt, int E) {
    int e = blockIdx.x * 256 + threadIdx.x;
    if (e >= E) return;
    int d = ei[E + e];
    int r = et[e];
    atomicAdd(&cnt[(size_t)d * RREL + r], 1);
}

__global__ void scan_block_kernel(const int* __restrict__ cnt, int* __restrict__ rploc,
                                  int* __restrict__ bsum, int N) {
    __shared__ int s[256];
    int t = threadIdx.x;
    int d = blockIdx.x * 256 + t;
    int v = 0;
    if (d < N) {
#pragma unroll
        for (int r = 0; r < RREL; ++r) v += cnt[(size_t)d * RREL + r];
    }
    s[t] = v;
    __syncthreads();
#pragma unroll
    for (int off = 1; off < 256; off <<= 1) {
        int u = 0;
        if (t >= off) u = s[t - off];
        __syncthreads();
        s[t] += u;
        __syncthreads();
    }
    if (d < N) rploc[d] = s[t] - v;
    if (t == 255) bsum[blockIdx.x] = s[255];
}

__global__ void scan_top_kernel(const int* __restrict__ bsum, int* __restrict__ boff, int nb) {
    __shared__ int s[256];
    int t = threadIdx.x;
    int v = (t < nb) ? bsum[t] : 0;
    s[t] = v;
    __syncthreads();
#pragma unroll
    for (int off = 1; off < 256; off <<= 1) {
        int u = 0;
        if (t >= off) u = s[t - off];
        __syncthreads();
        s[t] += u;
        __syncthreads();
    }
    boff[t] = s[t] - v;
}

__global__ void finalize_kernel(const int* __restrict__ cnt, const int* __restrict__ rploc,
                                const int* __restrict__ boff, int* __restrict__ rowptr2,
                                float* __restrict__ inv, int N) {
    int d = blockIdx.x * 256 + threadIdx.x;
    if (d >= N) return;
    int run = rploc[d] + boff[d >> 8];
#pragma unroll
    for (int r = 0; r < RREL; ++r) {
        int c = cnt[(size_t)d * RREL + r];
        rowptr2[(size_t)d * RREL + r] = run;
        inv[(size_t)d * RREL + r] = 1.0f / (float)max(c, 1);
        run += c;
    }
    if (d == N - 1) rowptr2[(size_t)N * RREL] = run;
}

__global__ void fill_kernel(const int* __restrict__ ei, const int* __restrict__ et,
                            int* __restrict__ cursor, const int* __restrict__ rowptr2,
                            int* __restrict__ ssrc, int E) {
    int e = blockIdx.x * 256 + threadIdx.x;
    if (e >= E) return;
    int d = ei[E + e];
    int r = et[e];
    int bin = d * RREL + r;
    int pos = rowptr2[bin] + atomicAdd(&cursor[bin], 1);
    ssrc[pos] = ei[e];
}

__global__ void tobf_kernel(const float* __restrict__ x, unsigned short* __restrict__ xb, long n) {
    long i = (long)blockIdx.x * blockDim.x + threadIdx.x;
    long stride = (long)gridDim.x * blockDim.x;
    for (; i < n; i += stride) xb[i] = f2bf(x[i]);
}

// WTa[layer][j][f][k] = W[j][k][f] (j<8) or root[k][f] (j==8), bf16
__global__ void wcat_kernel(const float* __restrict__ W1, const float* __restrict__ r1,
                            const float* __restrict__ W2, const float* __restrict__ r2,
                            unsigned short* __restrict__ WTa1, unsigned short* __restrict__ WTa2) {
    int id = blockIdx.x * 256 + threadIdx.x;
    const int per = NJ * H * H;
    if (id >= 2 * per) return;
    int b = id / per;
    int rem = id - b * per;
    int j = rem / (H * H);
    int fk = rem - j * (H * H);
    int f = fk >> 7, k = fk & 127;
    const float* W = b ? W2 : W1;
    const float* rt = b ? r2 : r1;
    float v = (j < RREL) ? W[((size_t)j * H + k) * H + f] : rt[(size_t)k * H + f];
    (b ? WTa2 : WTa1)[((size_t)j * H + f) * H + k] = f2bf(v);
}

// Y[j-j0][n][f] = (xin @ B_j)[n][f], bf16. 64-row tiles, B^T (WTa[j][f][k]) staged in LDS.
__global__ __launch_bounds__(256) void xw_kernel(const unsigned short* __restrict__ xin,
                                                 const unsigned short* __restrict__ WTa,
                                                 unsigned short* __restrict__ Y,
                                                 int N, int j0, int j1) {
    __shared__ unsigned short Xs[64][136];
    __shared__ unsigned short Ws[128][136];
    const int t = threadIdx.x;
    const int w = t >> 6, l = t & 63;
    const int m_base = blockIdx.x * 64;
    const int colb = l & 15, quad = l >> 4;
    const u16x8 uz = {0, 0, 0, 0, 0, 0, 0, 0};
    const f32x4 fz = {0.f, 0.f, 0.f, 0.f};

    // stage X tile once (64 rows x K=128)
#pragma unroll
    for (int p = 0; p < 4; ++p) {
        int c = p * 256 + t;
        int row = c >> 4, k8 = (c & 15) * 8;
        int gn = m_base + row;
        u16x8 v = uz;
        if (gn < N) v = *(const u16x8*)&xin[(size_t)gn * H + k8];
        *(u16x8*)&Xs[row][k8] = v;
    }

    for (int j = j0; j < j1; ++j) {
        __syncthreads();  // Xs ready (first iter) / Ws free (later iters)
#pragma unroll
        for (int p = 0; p < 8; ++p) {
            int c = p * 256 + t;
            int f = c >> 4, k8 = (c & 15) * 8;
            *(u16x8*)&Ws[f][k8] = *(const u16x8*)&WTa[((size_t)j * H + f) * H + k8];
        }
        __syncthreads();
        f32x4 acc[8];
#pragma unroll
        for (int n = 0; n < 8; ++n) acc[n] = fz;
#pragma unroll
        for (int ks = 0; ks < 4; ++ks) {
            int kl = ks * 32 + quad * 8;
            bf16x8 a = *(const bf16x8*)&Xs[w * 16 + colb][kl];
#pragma unroll
            for (int n = 0; n < 8; ++n) {
                bf16x8 b = *(const bf16x8*)&Ws[n * 16 + colb][kl];
                acc[n] = __builtin_amdgcn_mfma_f32_16x16x32_bf16(a, b, acc[n], 0, 0, 0);
            }
        }
        unsigned short* Yj = Y + (size_t)(j - j0) * N * H;
#pragma unroll
        for (int n = 0; n < 8; ++n) {
            int col = n * 16 + colb;
#pragma unroll
            for (int i = 0; i < 4; ++i) {
                int gn = m_base + w * 16 + quad * 4 + i;
                if (gn < N) Yj[(size_t)gn * H + col] = f2bf(acc[n][i]);
            }
        }
    }
}

// one 16-lane group per dst: tot = sum_{r in [j0,min(j1,8))} inv[d,r] * sum_{bin} Y[r-j0][src]
// (+ Y[8-j0][d] if j1==9) (+ accf[d] if j0>0) ; final: + bias, relu?, write outf/outb; else write accf
__global__ __launch_bounds__(256) void gather_kernel(const unsigned short* __restrict__ Y,
                                                     const float* __restrict__ inv,
                                                     const int* __restrict__ rowptr2,
                                                     const int* __restrict__ ssrc,
                                                     const float* __restrict__ bias,
                                                     float* __restrict__ accf,
                                                     float* __restrict__ outf,
                                                     unsigned short* __restrict__ outb,
                                                     int N, int relu, int j0, int j1, int final_pass) {
    const int t = threadIdx.x;
    const int l = t & 63;
    int d = blockIdx.x * 16 + (t >> 4);
    if (d >= N) return;
    const int fl = l & 15;
    const int kc = fl * 8;
    // lanes fl<9 hold rowptr2[d*8+fl]; fl<8 hold inv[d*8+fl]
    int rp = 0;
    float ivl = 0.f;
    if (fl < 9) rp = rowptr2[(size_t)d * RREL + fl];
    if (fl < 8) ivl = inv[(size_t)d * RREL + fl];
    const int gbase = l & 48;
    float tot[8] = {};
    int rend = (j1 < RREL) ? j1 : RREL;
    for (int r = j0; r < rend; ++r) {
        int beg = __shfl(rp, gbase + r);
        int end = __shfl(rp, gbase + r + 1);
        float iv = __shfl(ivl, gbase + r);
        const unsigned short* Yr = Y + (size_t)(r - j0) * N * H;
        float af[8] = {};
        int i = beg;
        for (; i + 1 < end; i += 2) {
            int s0 = ssrc[i];
            int s1 = ssrc[i + 1];
            u16x8 v0 = *(const u16x8*)&Yr[(size_t)s0 * H + kc];
            u16x8 v1 = *(const u16x8*)&Yr[(size_t)s1 * H + kc];
#pragma unroll
            for (int j = 0; j < 8; ++j)
                af[j] += bf2f((unsigned short)v0[j]) + bf2f((unsigned short)v1[j]);
        }
        if (i < end) {
            int s0 = ssrc[i];
            u16x8 v0 = *(const u16x8*)&Yr[(size_t)s0 * H + kc];
#pragma unroll
            for (int j = 0; j < 8; ++j) af[j] += bf2f((unsigned short)v0[j]);
        }
#pragma unroll
        for (int j = 0; j < 8; ++j) tot[j] += af[j] * iv;
    }
    if (j1 == NJ) {
        // root contribution for this dst
        u16x8 vr = *(const u16x8*)&Y[((size_t)(RREL - j0) * N + d) * H + kc];
#pragma unroll
        for (int j = 0; j < 8; ++j) tot[j] += bf2f((unsigned short)vr[j]);
    }
    if (j0 > 0) {
        f32x4 p0 = *(const f32x4*)&accf[(size_t)d * H + kc];
        f32x4 p1 = *(const f32x4*)&accf[(size_t)d * H + kc + 4];
#pragma unroll
        for (int j = 0; j < 4; ++j) { tot[j] += p0[j]; tot[4 + j] += p1[j]; }
    }
    if (final_pass) {
        f32x4 b0 = *(const f32x4*)&bias[kc];
        f32x4 b1 = *(const f32x4*)&bias[kc + 4];
#pragma unroll
        for (int j = 0; j < 4; ++j) { tot[j] += b0[j]; tot[4 + j] += b1[j]; }
        if (relu) {
#pragma unroll
            for (int j = 0; j < 8; ++j) tot[j] = fmaxf(tot[j], 0.f);
        }
        if (outf) {
            f32x4 o0, o1;
#pragma unroll
            for (int j = 0; j < 4; ++j) { o0[j] = tot[j]; o1[j] = tot[4 + j]; }
            *(f32x4*)&outf[(size_t)d * H + kc] = o0;
            *(f32x4*)&outf[(size_t)d * H + kc + 4] = o1;
        } else {
            u16x8 o;
#pragma unroll
            for (int j = 0; j < 8; ++j) o[j] = f2bf(tot[j]);
            *(u16x8*)&outb[(size_t)d * H + kc] = o;
        }
    } else {
        f32x4 o0, o1;
#pragma unroll
        for (int j = 0; j < 4; ++j) { o0[j] = tot[j]; o1[j] = tot[4 + j]; }
        *(f32x4*)&accf[(size_t)d * H + kc] = o0;
        *(f32x4*)&accf[(size_t)d * H + kc + 4] = o1;
    }
}

extern "C" void kernel_launch(void* const* d_in, const int* in_sizes, int n_in,
                              void* d_out, int out_size, void* d_ws, size_t ws_size,
                              hipStream_t stream) {
    const int* edge_index = (const int*)d_in[0];
    const int* edge_type  = (const int*)d_in[1];
    const float* node_emb = (const float*)d_in[2];
    const float* W1    = (const float*)d_in[3];
    const float* root1 = (const float*)d_in[4];
    const float* b1    = (const float*)d_in[5];
    const float* W2    = (const float*)d_in[6];
    const float* root2 = (const float*)d_in[7];
    const float* b2    = (const float*)d_in[8];
    float* out = (float*)d_out;

    const int E = in_sizes[1];
    const int N = in_sizes[2] / H;

    char* base = (char*)d_ws;
    size_t off = 0;
    auto take = [&](size_t bytes) { size_t o = off; off = (off + bytes + 63) & ~(size_t)63; return o; };
    int*   cnt     = (int*)  (base + take((size_t)N * RREL * 4));
    int*   cursor  = (int*)  (base + take((size_t)N * RREL * 4));
    int*   rploc   = (int*)  (base + take((size_t)N * 4));
    int*   bsum    = (int*)  (base + take(256 * 4));
    int*   boff    = (int*)  (base + take(256 * 4));
    int*   rowptr2 = (int*)  (base + take(((size_t)N * RREL + 1) * 4));
    float* inv     = (float*)(base + take((size_t)N * RREL * 4));
    int*   ssrc    = (int*)  (base + take((size_t)E * 4));
    unsigned short* WTa1 = (unsigned short*)(base + take((size_t)NJ * H * H * 2));
    unsigned short* WTa2 = (unsigned short*)(base + take((size_t)NJ * H * H * 2));
    unsigned short* xb  = (unsigned short*)(base + take((size_t)N * H * 2));
    unsigned short* hb  = (unsigned short*)(base + take((size_t)N * H * 2));

    // Y: try full 9-slab layout; else fallback with fp32 accumulator + relation chunks
    size_t fixed_off = off;
    unsigned short* Y;
    float* accf = nullptr;
    int rc;
    size_t availA = (ws_size > fixed_off) ? ws_size - fixed_off : 0;
    if (availA >= (size_t)NJ * N * H * 2) {
        Y = (unsigned short*)(base + fixed_off);
        rc = NJ;
    } else {
        accf = (float*)(base + fixed_off);
        size_t off2 = fixed_off + (((size_t)N * H * 4 + 63) & ~(size_t)63);
        Y = (unsigned short*)(base + off2);
        size_t availB = (ws_size > off2) ? ws_size - off2 : 0;
        rc = (int)(availB / ((size_t)N * H * 2));
        if (rc > RREL) rc = RREL;
        if (rc < 1) rc = 1;
    }

    const int nbScan = (N + 255) / 256;

    zero_kernel<<<512, 256, 0, stream>>>(cnt, (long)N * RREL * 2);  // cnt + cursor
    count_kernel<<<(E + 255) / 256, 256, 0, stream>>>(edge_index, edge_type, cnt, E);
    scan_block_kernel<<<nbScan, 256, 0, stream>>>(cnt, rploc, bsum, N);
    scan_top_kernel<<<1, 256, 0, stream>>>(bsum, boff, nbScan);
    finalize_kernel<<<nbScan, 256, 0, stream>>>(cnt, rploc, boff, rowptr2, inv, N);
    fill_kernel<<<(E + 255) / 256, 256, 0, stream>>>(edge_index, edge_type, cursor, rowptr2, ssrc, E);
    wcat_kernel<<<(2 * NJ * H * H + 255) / 256, 256, 0, stream>>>(W1, root1, W2, root2, WTa1, WTa2);
    tobf_kernel<<<1024, 256, 0, stream>>>(node_emb, xb, (long)N * H);

    const int gx = (N + 63) / 64;
    const int gg = (N + 15) / 16;

    auto run_layer = [&](const unsigned short* xin, const unsigned short* WTa, const float* bias,
                         float* of, unsigned short* ob, int relu) {
        for (int j0 = 0; j0 < NJ; j0 += rc) {
            int j1 = (j0 + rc < NJ) ? j0 + rc : NJ;
            int fin = (j1 == NJ);
            xw_kernel<<<gx, 256, 0, stream>>>(xin, WTa, Y, N, j0, j1);
            gather_kernel<<<gg, 256, 0, stream>>>(Y, inv, rowptr2, ssrc, bias, accf,
                                                  fin ? of : nullptr, fin ? ob : nullptr,
                                                  N, relu, j0, j1, fin);
        }
    };

    // layer 1: xb -> hb = relu(...) bf16 ; layer 2: hb -> out fp32
    run_layer(xb, WTa1, b1, nullptr, hb, 1);
    run_layer(hb, WTa2, b2, out, nullptr, 0);
}

// Round 7
// 281.512 us; speedup vs baseline: 1.7001x; 1.1793x over previous
//
#include <hip/hip_runtime.h>

#define H 128
#define RREL 8
#define NJ 9        // 8 relations + root

typedef short bf16x8 __attribute__((ext_vector_type(8)));
typedef float f32x4 __attribute__((ext_vector_type(4)));
typedef unsigned short u16x8 __attribute__((ext_vector_type(8)));

static __device__ __forceinline__ unsigned short f2bf(float f) {
    unsigned int u = __float_as_uint(f);
    unsigned int r = (u + 0x7fffu + ((u >> 16) & 1u)) >> 16;
    return (unsigned short)r;
}
static __device__ __forceinline__ float bf2f(unsigned short u) {
    return __uint_as_float(((unsigned int)u) << 16);
}

__global__ void zero_kernel(int* p, long n) {
    long i = (long)blockIdx.x * blockDim.x + threadIdx.x;
    long stride = (long)gridDim.x * blockDim.x;
    for (; i < n; i += stride) p[i] = 0;
}

__global__ void count_kernel(const int* __restrict__ ei, const int* __restrict__ et,
                             int* __restrict__ cnt, int E) {
    int e = blockIdx.x * 256 + threadIdx.x;
    if (e >= E) return;
    int d = ei[E + e];
    int r = et[e];
    atomicAdd(&cnt[(size_t)d * RREL + r], 1);
}

__global__ void scan_block_kernel(const int* __restrict__ cnt, int* __restrict__ rploc,
                                  int* __restrict__ bsum, int N) {
    __shared__ int s[256];
    int t = threadIdx.x;
    int d = blockIdx.x * 256 + t;
    int v = 0;
    if (d < N) {
#pragma unroll
        for (int r = 0; r < RREL; ++r) v += cnt[(size_t)d * RREL + r];
    }
    s[t] = v;
    __syncthreads();
#pragma unroll
    for (int off = 1; off < 256; off <<= 1) {
        int u = 0;
        if (t >= off) u = s[t - off];
        __syncthreads();
        s[t] += u;
        __syncthreads();
    }
    if (d < N) rploc[d] = s[t] - v;
    if (t == 255) bsum[blockIdx.x] = s[255];
}

__global__ void scan_top_kernel(const int* __restrict__ bsum, int* __restrict__ boff, int nb) {
    __shared__ int s[256];
    int t = threadIdx.x;
    int v = (t < nb) ? bsum[t] : 0;
    s[t] = v;
    __syncthreads();
#pragma unroll
    for (int off = 1; off < 256; off <<= 1) {
        int u = 0;
        if (t >= off) u = s[t - off];
        __syncthreads();
        s[t] += u;
        __syncthreads();
    }
    boff[t] = s[t] - v;
}

// rowptr[d] = global dst-bin start; inv[d*8+r] = 1/max(cnt,1); rowptr[N] = E
__global__ void finalize_kernel(const int* __restrict__ cnt, const int* __restrict__ rploc,
                                const int* __restrict__ boff, int* __restrict__ rowptr,
                                float* __restrict__ inv, int N) {
    int d = blockIdx.x * 256 + threadIdx.x;
    if (d >= N) return;
    int rp = rploc[d] + boff[d >> 8];
    rowptr[d] = rp;
    int deg = 0;
#pragma unroll
    for (int r = 0; r < RREL; ++r) {
        int c = cnt[(size_t)d * RREL + r];
        inv[(size_t)d * RREL + r] = 1.0f / (float)max(c, 1);
        deg += c;
    }
    if (d == N - 1) rowptr[N] = rp + deg;
}

// packed[pos] = src | (rel<<20), binned by dst
__global__ void fill_kernel(const int* __restrict__ ei, const int* __restrict__ et,
                            int* __restrict__ cursor, const int* __restrict__ rowptr,
                            int* __restrict__ packed, int E) {
    int e = blockIdx.x * 256 + threadIdx.x;
    if (e >= E) return;
    int d = ei[E + e];
    int pos = rowptr[d] + atomicAdd(&cursor[d], 1);
    packed[pos] = ei[e] | (et[e] << 20);
}

__global__ void tobf_kernel(const float* __restrict__ x, unsigned short* __restrict__ xb, long n) {
    long i = (long)blockIdx.x * blockDim.x + threadIdx.x;
    long stride = (long)gridDim.x * blockDim.x;
    for (; i < n; i += stride) xb[i] = f2bf(x[i]);
}

// WTa1[j][f][k] = W1[j][k][f] / root1[k][f]   (normal K)
// WTa2[j][f][k'] = W2[j][orig(k')][f] / root2[orig(k')][f]   (K permuted: orig(k')=(k'&7)*16+(k'>>3))
// biasP[0][c'] = b1[orig(c')], biasP[1][c'] = b2[orig(c')]
__global__ void wcat_kernel(const float* __restrict__ W1, const float* __restrict__ r1,
                            const float* __restrict__ W2, const float* __restrict__ r2,
                            const float* __restrict__ b1, const float* __restrict__ b2,
                            unsigned short* __restrict__ WTa1, unsigned short* __restrict__ WTa2,
                            float* __restrict__ biasP) {
    int id = blockIdx.x * 256 + threadIdx.x;
    const int per = NJ * H * H;
    if (id < per) {
        int j = id / (H * H);
        int fk = id - j * (H * H);
        int f = fk >> 7, k = fk & 127;
        float v = (j < RREL) ? W1[((size_t)j * H + k) * H + f] : r1[(size_t)k * H + f];
        WTa1[id] = f2bf(v);
        int ko = (k & 7) * 16 + (k >> 3);
        float v2 = (j < RREL) ? W2[((size_t)j * H + ko) * H + f] : r2[(size_t)ko * H + f];
        WTa2[id] = f2bf(v2);
    } else if (id < per + 2 * H) {
        int c = id - per;
        int cp = c & 127;
        int co = (cp & 7) * 16 + (cp >> 3);
        biasP[c] = (c < H) ? b1[co] : b2[co];
    }
}

// Y[j-j0][n][c'] = (xin @ B_j)[n][orig(c')], bf16, cols permuted.
// M=128 tile, A-frags from global, B staged in LDS.
__global__ __launch_bounds__(256) void xw_kernel(const unsigned short* __restrict__ xin,
                                                 const unsigned short* __restrict__ WTa,
                                                 unsigned short* __restrict__ Y,
                                                 int N, int j0, int j1) {
    __shared__ unsigned short Ws[128][136];
    const int t = threadIdx.x;
    const int w = t >> 6, l = t & 63;
    const int m_base = blockIdx.x * 128;
    const int colb = l & 15, quad = l >> 4;
    const f32x4 fz = {0.f, 0.f, 0.f, 0.f};

    // A rows for this lane (clamped; OOB rows' results discarded at store)
    int row0 = m_base + w * 32 + colb;
    int row1 = row0 + 16;
    const unsigned short* xr0 = xin + (size_t)(row0 < N ? row0 : N - 1) * H;
    const unsigned short* xr1 = xin + (size_t)(row1 < N ? row1 : N - 1) * H;

    for (int j = j0; j < j1; ++j) {
        __syncthreads();
#pragma unroll
        for (int p = 0; p < 8; ++p) {
            int c = p * 256 + t;
            int f = c >> 4, k8 = (c & 15) * 8;
            *(u16x8*)&Ws[f][k8] = *(const u16x8*)&WTa[((size_t)j * H + f) * H + k8];
        }
        __syncthreads();
        f32x4 acc[2][8];
#pragma unroll
        for (int mi = 0; mi < 2; ++mi)
#pragma unroll
            for (int n = 0; n < 8; ++n) acc[mi][n] = fz;
#pragma unroll
        for (int ks = 0; ks < 4; ++ks) {
            int kl = ks * 32 + quad * 8;
            bf16x8 a0 = *(const bf16x8*)&xr0[kl];
            bf16x8 a1 = *(const bf16x8*)&xr1[kl];
#pragma unroll
            for (int n = 0; n < 8; ++n) {
                bf16x8 b = *(const bf16x8*)&Ws[n * 16 + colb][kl];
                acc[0][n] = __builtin_amdgcn_mfma_f32_16x16x32_bf16(a0, b, acc[0][n], 0, 0, 0);
                acc[1][n] = __builtin_amdgcn_mfma_f32_16x16x32_bf16(a1, b, acc[1][n], 0, 0, 0);
            }
        }
        unsigned short* Yj = Y + (size_t)(j - j0) * N * H;
#pragma unroll
        for (int mi = 0; mi < 2; ++mi) {
#pragma unroll
            for (int i = 0; i < 4; ++i) {
                int row = m_base + w * 32 + mi * 16 + quad * 4 + i;
                if (row < N) {
                    u16x8 o;
#pragma unroll
                    for (int n = 0; n < 8; ++n) o[n] = f2bf(acc[mi][n][i]);
                    *(u16x8*)&Yj[(size_t)row * H + colb * 8] = o;  // col' = colb*8 + n
                }
            }
        }
    }
}

// one 16-lane group per dst; packed edges (src | r<<20), dst-contiguous.
// tot[c'] = sum_edges(r in [j0,jr)) inv[d,r]*Y[r-j0][src][c'] (+ Y[8-j0][d] if j1==9)
// (+ accf if j0>0); final: +biasP, relu?, write out (fp32 unscrambled) or hb (bf16 permuted)
__global__ __launch_bounds__(256) void gather_kernel(const unsigned short* __restrict__ Y,
                                                     const float* __restrict__ inv,
                                                     const int* __restrict__ rowptr,
                                                     const int* __restrict__ packed,
                                                     const float* __restrict__ biasP,
                                                     float* __restrict__ accf,
                                                     float* __restrict__ outf,
                                                     unsigned short* __restrict__ outb,
                                                     int N, int relu, int j0, int j1, int final_pass) {
    const int t = threadIdx.x;
    const int l = t & 63;
    int d = blockIdx.x * 16 + (t >> 4);
    if (d >= N) return;
    const int fl = l & 15;
    const int kc = fl * 8;
    const int gbase = l & 48;
    int rp = 0;
    if (fl < 2) rp = rowptr[d + fl];
    float ivl = 0.f;
    if (fl < 8) ivl = inv[(size_t)d * RREL + fl];
    int beg = __shfl(rp, gbase);
    int end = __shfl(rp, gbase + 1);
    const int jr = (j1 < RREL) ? j1 : RREL;
    float tot[8] = {};
    for (int i = beg; i < end; i += 16) {
        int pk = (i + fl < end) ? packed[i + fl] : 0;
        int m = end - i;
        if (m > 16) m = 16;
        int e = 0;
        for (; e + 1 < m; e += 2) {
            int v0 = __shfl(pk, gbase + e);
            int v1 = __shfl(pk, gbase + e + 1);
            int s0 = v0 & 0xFFFFF, r0 = v0 >> 20;
            int s1 = v1 & 0xFFFFF, r1 = v1 >> 20;
            if (r0 >= j0 && r0 < jr) {
                float iv = __shfl(ivl, gbase + r0);
                u16x8 v = *(const u16x8*)&Y[((size_t)(r0 - j0) * N + s0) * H + kc];
#pragma unroll
                for (int j = 0; j < 8; ++j) tot[j] += iv * bf2f((unsigned short)v[j]);
            }
            if (r1 >= j0 && r1 < jr) {
                float iv = __shfl(ivl, gbase + r1);
                u16x8 v = *(const u16x8*)&Y[((size_t)(r1 - j0) * N + s1) * H + kc];
#pragma unroll
                for (int j = 0; j < 8; ++j) tot[j] += iv * bf2f((unsigned short)v[j]);
            }
        }
        if (e < m) {
            int v0 = __shfl(pk, gbase + e);
            int s0 = v0 & 0xFFFFF, r0 = v0 >> 20;
            if (r0 >= j0 && r0 < jr) {
                float iv = __shfl(ivl, gbase + r0);
                u16x8 v = *(const u16x8*)&Y[((size_t)(r0 - j0) * N + s0) * H + kc];
#pragma unroll
                for (int j = 0; j < 8; ++j) tot[j] += iv * bf2f((unsigned short)v[j]);
            }
        }
    }
    if (j1 == NJ) {
        u16x8 vr = *(const u16x8*)&Y[((size_t)(RREL - j0) * N + d) * H + kc];
#pragma unroll
        for (int j = 0; j < 8; ++j) tot[j] += bf2f((unsigned short)vr[j]);
    }
    if (j0 > 0) {
        f32x4 p0 = *(const f32x4*)&accf[(size_t)d * H + kc];
        f32x4 p1 = *(const f32x4*)&accf[(size_t)d * H + kc + 4];
#pragma unroll
        for (int j = 0; j < 4; ++j) { tot[j] += p0[j]; tot[4 + j] += p1[j]; }
    }
    if (final_pass) {
        f32x4 b0 = *(const f32x4*)&biasP[kc];
        f32x4 b1 = *(const f32x4*)&biasP[kc + 4];
#pragma unroll
        for (int j = 0; j < 4; ++j) { tot[j] += b0[j]; tot[4 + j] += b1[j]; }
        if (relu) {
#pragma unroll
            for (int j = 0; j < 8; ++j) tot[j] = fmaxf(tot[j], 0.f);
        }
        if (outf) {
            // unscramble: stored index kc+j holds orig col j*16+fl
#pragma unroll
            for (int j = 0; j < 8; ++j) outf[(size_t)d * H + j * 16 + fl] = tot[j];
        } else {
            u16x8 o;
#pragma unroll
            for (int j = 0; j < 8; ++j) o[j] = f2bf(tot[j]);
            *(u16x8*)&outb[(size_t)d * H + kc] = o;
        }
    } else {
        f32x4 o0, o1;
#pragma unroll
        for (int j = 0; j < 4; ++j) { o0[j] = tot[j]; o1[j] = tot[4 + j]; }
        *(f32x4*)&accf[(size_t)d * H + kc] = o0;
        *(f32x4*)&accf[(size_t)d * H + kc + 4] = o1;
    }
}

extern "C" void kernel_launch(void* const* d_in, const int* in_sizes, int n_in,
                              void* d_out, int out_size, void* d_ws, size_t ws_size,
                              hipStream_t stream) {
    const int* edge_index = (const int*)d_in[0];
    const int* edge_type  = (const int*)d_in[1];
    const float* node_emb = (const float*)d_in[2];
    const float* W1    = (const float*)d_in[3];
    const float* root1 = (const float*)d_in[4];
    const float* b1    = (const float*)d_in[5];
    const float* W2    = (const float*)d_in[6];
    const float* root2 = (const float*)d_in[7];
    const float* b2    = (const float*)d_in[8];
    float* out = (float*)d_out;

    const int E = in_sizes[1];
    const int N = in_sizes[2] / H;

    char* base = (char*)d_ws;
    size_t off = 0;
    auto take = [&](size_t bytes) { size_t o = off; off = (off + bytes + 63) & ~(size_t)63; return o; };
    int*   cnt     = (int*)  (base + take((size_t)N * RREL * 4));
    int*   cursor  = (int*)  (base + take((size_t)N * 4));   // adjacent to cnt: single zero pass
    int*   rploc   = (int*)  (base + take((size_t)N * 4));
    int*   bsum    = (int*)  (base + take(256 * 4));
    int*   boff    = (int*)  (base + take(256 * 4));
    int*   rowptr  = (int*)  (base + take(((size_t)N + 1) * 4));
    float* inv     = (float*)(base + take((size_t)N * RREL * 4));
    int*   packed  = (int*)  (base + take((size_t)E * 4));
    unsigned short* WTa1 = (unsigned short*)(base + take((size_t)NJ * H * H * 2));
    unsigned short* WTa2 = (unsigned short*)(base + take((size_t)NJ * H * H * 2));
    float* biasP   = (float*)(base + take(2 * H * 4));
    unsigned short* xb  = (unsigned short*)(base + take((size_t)N * H * 2));
    unsigned short* hb  = (unsigned short*)(base + take((size_t)N * H * 2));

    // Y: full 9-slab if it fits, else fp32 accumulator + relation chunks
    size_t fixed_off = off;
    unsigned short* Y;
    float* accf = nullptr;
    int rc;
    size_t availA = (ws_size > fixed_off) ? ws_size - fixed_off : 0;
    if (availA >= (size_t)NJ * N * H * 2) {
        Y = (unsigned short*)(base + fixed_off);
        rc = NJ;
    } else {
        accf = (float*)(base + fixed_off);
        size_t off2 = fixed_off + (((size_t)N * H * 4 + 63) & ~(size_t)63);
        Y = (unsigned short*)(base + off2);
        size_t availB = (ws_size > off2) ? ws_size - off2 : 0;
        rc = (int)(availB / ((size_t)N * H * 2));
        if (rc > RREL) rc = RREL;
        if (rc < 1) rc = 1;
    }

    const int nbScan = (N + 255) / 256;

    zero_kernel<<<512, 256, 0, stream>>>(cnt, (long)N * (RREL + 1));  // cnt + cursor
    count_kernel<<<(E + 255) / 256, 256, 0, stream>>>(edge_index, edge_type, cnt, E);
    scan_block_kernel<<<nbScan, 256, 0, stream>>>(cnt, rploc, bsum, N);
    scan_top_kernel<<<1, 256, 0, stream>>>(bsum, boff, nbScan);
    finalize_kernel<<<nbScan, 256, 0, stream>>>(cnt, rploc, boff, rowptr, inv, N);
    fill_kernel<<<(E + 255) / 256, 256, 0, stream>>>(edge_index, edge_type, cursor, rowptr, packed, E);
    wcat_kernel<<<(NJ * H * H + 2 * H + 255) / 256, 256, 0, stream>>>(W1, root1, W2, root2, b1, b2,
                                                                      WTa1, WTa2, biasP);
    tobf_kernel<<<1024, 256, 0, stream>>>(node_emb, xb, (long)N * H);

    const int gx = (N + 127) / 128;
    const int gg = (N + 15) / 16;

    auto run_layer = [&](const unsigned short* xin, const unsigned short* WTa, const float* bp,
                         float* of, unsigned short* ob, int relu) {
        for (int j0 = 0; j0 < NJ; j0 += rc) {
            int j1 = (j0 + rc < NJ) ? j0 + rc : NJ;
            int fin = (j1 == NJ);
            xw_kernel<<<gx, 256, 0, stream>>>(xin, WTa, Y, N, j0, j1);
            gather_kernel<<<gg, 256, 0, stream>>>(Y, inv, rowptr, packed, bp, accf,
                                                  fin ? of : nullptr, fin ? ob : nullptr,
                                                  N, relu, j0, j1, fin);
        }
    };

    run_layer(xb, WTa1, biasP, nullptr, hb, 1);
    run_layer(hb, WTa2, biasP + H, out, nullptr, 0);
}